// Round 9
// baseline (1853.355 us; speedup 1.0000x reference)
//
#include <hip/hip_runtime.h>
#include <hip/hip_bf16.h>

// ---------------------------------------------------------------------------
// RelationalNetwork: N=32, C=24, H=W=14, O=196, HD=128, GH=256, AS=28
// pairs[n,i,j] = [feats[n,j](26), feats[n,i](26), code[n](128)]  (D_IN=180)
// h1 = relu(AJ'[n,j] + BI[n,i])        AJ' has CC (code-term) + gb0 folded in
// h  = relu(h@gw{1,2,3}+gb)            fused, bf16 MFMA 32x32x16, LDS-resident
// relations[n] = sum over 196^2 pairs  -> head MLP (fp32, tiny)
//
// Round 9: persistent ping-pong. Register-cap lesson locked in (r3/r4/r8:
// any cap <128 spills 0.5-1.5GB => only (512,4) is viable; occupancy capped
// at 4 waves/SIMD). So attack the OTHER costs: barrier convoy + exposed
// phase-0 latency. Persistent 512 blocks x ~38 chunks each; ping-pong hA/hB;
// 3 barriers/chunk (was 5-7); phase-0 of chunk c+1 (global AJ/BI loads +
// LDS build into the free buffer) overlaps layer-3 MFMAs of chunk c (T14);
// per-layer W fragments prefetched across the preceding barrier. SWZ16
// bijective swizzle (r8-verified). setprio around MFMA pairs.
// Tripwire: WRITE_SIZE >> 25MB => persistent-loop state spilled => revert.
// ---------------------------------------------------------------------------

typedef __attribute__((ext_vector_type(8))) short short8;
typedef __attribute__((ext_vector_type(16))) float f32x16;

#define NIMG 32
#define O 196
#define GH 256
#define AS 28
#define ROWS 64
#define CHUNKS 601          // 600*64 + 16 = 38416 (tail chunk: 16 valid rows)
#define TOTALC (NIMG * CHUNKS)
#define GRID 512

#define SWZ16(row) (((row) & 15) << 4)

static __device__ __forceinline__ unsigned short f2bf(float f) {
    __hip_bfloat16 h = __float2bfloat16(f);
    return *reinterpret_cast<unsigned short*>(&h);
}

// ---- setup kernel B: CC[n,g] = code[n] @ gw0[52:180] + gb0 -----------------
__global__ void k_cc(const float* __restrict__ code, const float* __restrict__ gw0,
                     const float* __restrict__ gb0, float* __restrict__ CC) {
    const int n = blockIdx.x, g = threadIdx.x;
    __shared__ float cs[128];
    if (g < 128) cs[g] = code[n * 128 + g];
    __syncthreads();
    float acc = gb0[g];
    for (int k = 0; k < 128; ++k) acc = fmaf(cs[k], gw0[(52 + k) * GH + g], acc);
    CC[n * GH + g] = acc;
}

// ---- setup kernel A: AJ'[n,p,g] (includes CC), BI[n,p,g] -------------------
__global__ void k_ajbi(const float* __restrict__ x, const float* __restrict__ gw0,
                       const float* __restrict__ CC,
                       float* __restrict__ AJ, float* __restrict__ BI) {
    const int np = blockIdx.x;            // n*196 + p
    const int n = np / O, p = np - n * O;
    const int g = threadIdx.x;
    __shared__ float fs[26];
    if (g < 24)       fs[g]  = x[(n * 24 + g) * O + p];
    else if (g == 24) fs[24] = -7.0f + (float)(p / 14) * (14.0f / 13.0f);
    else if (g == 25) fs[25] = -7.0f + (float)(p % 14) * (14.0f / 13.0f);
    __syncthreads();
    float aj = CC[n * GH + g], bi = 0.f;
#pragma unroll
    for (int c = 0; c < 26; ++c) {
        const float f = fs[c];
        aj = fmaf(f, gw0[c * GH + g], aj);
        bi = fmaf(f, gw0[(26 + c) * GH + g], bi);
    }
    AJ[np * GH + g] = aj;
    BI[np * GH + g] = bi;
}

// ---- setup kernel C: pack gw1/2/3 into 32x32x16 B-fragment layout ----------
// elem offset = L*65536 + nt*8192 + ks*512 + lane*8 + e
// value = W[ks*16 + (lane>>5)*8 + e][nt*32 + (lane&31)]
// (serves as either operand: B-frag for W, or A-frag for W^T under swap)
__global__ void k_pack(const float* __restrict__ gw1, const float* __restrict__ gw2,
                       const float* __restrict__ gw3, unsigned short* __restrict__ pW) {
    const int idx = blockIdx.x * 256 + threadIdx.x;     // 3*65536 total
    const int L = idx >> 16;
    const int rem = idx & 0xFFFF;
    const int e = rem & 7;
    const int lane = (rem >> 3) & 63;
    const int ks = (rem >> 9) & 15;
    const int nt = rem >> 13;                            // 0..7 (column 32-slice)
    const int k = ks * 16 + ((lane >> 5) << 3) + e;
    const int col = nt * 32 + (lane & 31);
    const float* W = (L == 0) ? gw1 : (L == 1) ? gw2 : gw3;
    pW[idx] = f2bf(W[k * GH + col]);
}

// ---- main fused persistent kernel ------------------------------------------
__global__ __launch_bounds__(512, 4) void k_main(
    const float* __restrict__ AJ, const float* __restrict__ BI,
    const unsigned short* __restrict__ pW,
    const float* __restrict__ gb1, const float* __restrict__ gb2,
    const float* __restrict__ gb3, float* __restrict__ rel) {
    __shared__ __attribute__((aligned(16))) unsigned short hA[ROWS * GH];
    __shared__ __attribute__((aligned(16))) unsigned short hB[ROWS * GH];

    const int t = threadIdx.x;
    const int wave = t >> 6;              // 0..7 (= N-slice, cols wave*32..+31)
    const int lane = t & 63;
    const int l31 = lane & 31;
    const int hi = lane >> 5;
    const int l15 = lane & 15;
    const int X = SWZ16(l15);
    const int hi16 = hi << 4;
    const int arow = l31 * 512;

    const short8* wpb = (const short8*)pW + wave * 1024;   // wave's 32-col slice
    const float bias3 = gb3[wave * 32 + l31];

    unsigned short* pA = hA;
    unsigned short* pB = hB;

    // phase-0: h1 = relu(AJ'[j] + BI[i]) -> dst (bf16, swizzled)
    auto p0 = [&](unsigned short* dst, int gg) {
        const int n = gg / CHUNKS;
        const int chunk = gg - n * CHUNKS;
        const int row_base = chunk * ROWS;
        const int i0 = row_base / O;
        const int j00 = row_base - i0 * O;
        const int i1 = min(i0 + 1, O - 1);
        const float4 bi0 = *(const float4*)&BI[(n * O + i0) * GH + lane * 4];
        const float4 bi1 = *(const float4*)&BI[(n * O + i1) * GH + lane * 4];
#pragma unroll
        for (int e = 0; e < 8; ++e) {
            const int r = wave + e * 8;
            const int jj = j00 + r;                 // one wrap max (<=258)
            const bool wrap = (jj >= O);
            const int j = wrap ? jj - O : jj;       // tail garbage rows; masked later
            const float4 aj = *(const float4*)&AJ[(n * O + j) * GH + lane * 4];
            const float4 bi = wrap ? bi1 : bi0;
            const unsigned lo = (unsigned)f2bf(fmaxf(aj.x + bi.x, 0.f)) |
                                ((unsigned)f2bf(fmaxf(aj.y + bi.y, 0.f)) << 16);
            const unsigned hh = (unsigned)f2bf(fmaxf(aj.z + bi.z, 0.f)) |
                                ((unsigned)f2bf(fmaxf(aj.w + bi.w, 0.f)) << 16);
            const int byteoff = r * 512 + ((lane * 8) ^ SWZ16(r));
            uint2 dd; dd.x = lo; dd.y = hh;
            *(uint2*)((char*)dst + byteoff) = dd;
        }
    };

    short8 wa, wb, wc, wd;                // rotating W-fragment prefetch regs
    auto kloop = [&](const unsigned short* buf, const short8* wp,
                     f32x16& a0, f32x16& a1, bool swapped) {
        const char* hb = (const char*)buf + arow;
#pragma unroll
        for (int ks = 0; ks < 16; ++ks) {
            const short8 W = (ks & 3) == 0 ? wa : (ks & 3) == 1 ? wb
                           : (ks & 3) == 2 ? wc : wd;
            const int off = (ks * 32 + hi16) ^ X;
            const short8 h0 = *(const short8*)(hb + off);
            const short8 h1 = *(const short8*)(hb + off + 16384);   // +32 rows
            __builtin_amdgcn_s_setprio(1);
            if (swapped) {
                a0 = __builtin_amdgcn_mfma_f32_32x32x16_bf16(W, h0, a0, 0, 0, 0);
                a1 = __builtin_amdgcn_mfma_f32_32x32x16_bf16(W, h1, a1, 0, 0, 0);
            } else {
                a0 = __builtin_amdgcn_mfma_f32_32x32x16_bf16(h0, W, a0, 0, 0, 0);
                a1 = __builtin_amdgcn_mfma_f32_32x32x16_bf16(h1, W, a1, 0, 0, 0);
            }
            __builtin_amdgcn_s_setprio(0);
            if (ks < 12) {
                const short8 nw = wp[(ks + 4) * 64 + lane];
                if ((ks & 3) == 0) wa = nw; else if ((ks & 3) == 1) wb = nw;
                else if ((ks & 3) == 2) wc = nw; else wd = nw;
            }
        }
    };

    // swapped epilogue: C'[reg->W-col, lane->h-row]; col pairs packed b32
    auto epi = [&](const f32x16& a0, const f32x16& a1, const float* gb,
                   unsigned short* dst) {
        const float4 b40 = *(const float4*)&gb[wave * 32 + 0  + 4 * hi];
        const float4 b41 = *(const float4*)&gb[wave * 32 + 8  + 4 * hi];
        const float4 b42 = *(const float4*)&gb[wave * 32 + 16 + 4 * hi];
        const float4 b43 = *(const float4*)&gb[wave * 32 + 24 + 4 * hi];
        const float bias[16] = {b40.x, b40.y, b40.z, b40.w, b41.x, b41.y, b41.z, b41.w,
                                b42.x, b42.y, b42.z, b42.w, b43.x, b43.y, b43.z, b43.w};
        char* w0 = (char*)dst + l31 * 512;
#pragma unroll
        for (int rp = 0; rp < 8; ++rp) {
            const int r0 = rp * 2;
            const float ba = bias[(r0 >> 2) * 4 + (r0 & 3)];
            const float bb = bias[(r0 >> 2) * 4 + (r0 & 3) + 1];
            const int cw = (r0 & 3) + 8 * (r0 >> 2);           // col within slice (-4hi)
            const int cb = (wave * 64 + cw * 2 + hi * 8) ^ X;  // swizzled col byte
            const unsigned q0 = (unsigned)f2bf(fmaxf(a0[r0] + ba, 0.f)) |
                                ((unsigned)f2bf(fmaxf(a0[r0 + 1] + bb, 0.f)) << 16);
            const unsigned q1 = (unsigned)f2bf(fmaxf(a1[r0] + ba, 0.f)) |
                                ((unsigned)f2bf(fmaxf(a1[r0 + 1] + bb, 0.f)) << 16);
            *(unsigned*)(w0 + cb) = q0;
            *(unsigned*)(w0 + 16384 + cb) = q1;
        }
    };

    const f32x16 z = {0.f,0.f,0.f,0.f,0.f,0.f,0.f,0.f,0.f,0.f,0.f,0.f,0.f,0.f,0.f,0.f};

    int g = blockIdx.x;
    p0(pA, g);                                            // prime first chunk
    wa = wpb[lane]; wb = wpb[64 + lane]; wc = wpb[128 + lane]; wd = wpb[192 + lane];
    __syncthreads();

    for (;;) {
        const int n = g / CHUNKS;
        const bool tail = (g - n * CHUNKS) == (CHUNKS - 1);

        // ---- layer 1: read pA, epi -> pB ----
        f32x16 a0 = z, a1 = z;
        kloop(pA, wpb, a0, a1, true);
        wa = wpb[8192 + lane];        wb = wpb[8192 + 64 + lane];   // L2 prefetch
        wc = wpb[8192 + 128 + lane];  wd = wpb[8192 + 192 + lane];
        epi(a0, a1, gb1, pB);
        __syncthreads();

        // ---- layer 2: read pB, epi -> pA ----
        a0 = z; a1 = z;
        kloop(pB, wpb + 8192, a0, a1, true);
        wa = wpb[16384 + lane];       wb = wpb[16384 + 64 + lane];  // L3 prefetch
        wc = wpb[16384 + 128 + lane]; wd = wpb[16384 + 192 + lane];
        epi(a0, a1, gb2, pA);
        __syncthreads();

        // ---- layer 3 (unswapped): read pA; pB is FREE -> overlap next p0 ----
        a0 = z; a1 = z;
        kloop(pA, wpb + 16384, a0, a1, false);

        const int gn = g + GRID;
        const bool more = (gn < TOTALC);
        if (more) p0(pB, gn);                 // overlaps final-sum VALU below
        wa = wpb[lane]; wb = wpb[64 + lane];  // next-chunk L1 prefetch
        wc = wpb[128 + lane]; wd = wpb[192 + lane];

        // bias + relu + column-sum; lanes (l, l+32) share a column.
        {
            float s = 0.f;
            if (!tail) {
#pragma unroll
                for (int r = 0; r < 16; ++r)
                    s += fmaxf(a0[r] + bias3, 0.f) + fmaxf(a1[r] + bias3, 0.f);
            } else {
                // valid rows 0..15 -> tile0 regs 0..7 ((r&3)+8*(r>>2)+4hi < 16)
#pragma unroll
                for (int r = 0; r < 8; ++r)
                    s += fmaxf(a0[r] + bias3, 0.f);
            }
            s += __shfl_xor(s, 32);
            if (hi == 0) atomicAdd(&rel[n * GH + wave * 32 + l31], s);
        }

        if (!more) break;
        unsigned short* tmp = pA; pA = pB; pB = tmp;
        g = gn;
        __syncthreads();                      // p0 writes visible; L3 reads done
    }
}

// ---- head MLP (fp32, tiny): relations -> logits ----------------------------
__global__ void k_fmlp(const float* __restrict__ rel,
                       const float* __restrict__ fw0, const float* __restrict__ fb0,
                       const float* __restrict__ fw1, const float* __restrict__ fb1,
                       const float* __restrict__ fw2, const float* __restrict__ fb2,
                       float* __restrict__ out) {
    __shared__ float b0[GH], b1[GH];
    const int n = blockIdx.x, g = threadIdx.x;
    b0[g] = rel[n * GH + g];
    __syncthreads();
    float a = fb0[g];
    for (int k = 0; k < GH; ++k) a = fmaf(b0[k], fw0[k * GH + g], a);
    b1[g] = fmaxf(a, 0.f);
    __syncthreads();
    float c = fb1[g];
    for (int k = 0; k < GH; ++k) c = fmaf(b1[k], fw1[k * GH + g], c);
    b0[g] = fmaxf(c, 0.f);
    __syncthreads();
    if (g < AS) {
        float o = fb2[g];
        for (int k = 0; k < GH; ++k) o = fmaf(b0[k], fw2[k * AS + g], o);
        out[n * AS + g] = o;
    }
}

// ---------------------------------------------------------------------------
extern "C" void kernel_launch(void* const* d_in, const int* in_sizes, int n_in,
                              void* d_out, int out_size, void* d_ws, size_t ws_size,
                              hipStream_t stream) {
    const float* x    = (const float*)d_in[0];
    const float* code = (const float*)d_in[1];
    const float* gw0  = (const float*)d_in[2];
    const float* gb0  = (const float*)d_in[3];
    const float* gw1  = (const float*)d_in[4];
    const float* gb1  = (const float*)d_in[5];
    const float* gw2  = (const float*)d_in[6];
    const float* gb2  = (const float*)d_in[7];
    const float* gw3  = (const float*)d_in[8];
    const float* gb3  = (const float*)d_in[9];
    const float* fw0  = (const float*)d_in[10];
    const float* fb0  = (const float*)d_in[11];
    const float* fw1  = (const float*)d_in[12];
    const float* fb1  = (const float*)d_in[13];
    const float* fw2  = (const float*)d_in[14];
    const float* fb2  = (const float*)d_in[15];
    float* out = (float*)d_out;

    char* ws = (char*)d_ws;
    // workspace layout (16B aligned)
    float*          AJ  = (float*)(ws + 0);                 // 32*196*256*4 = 6,422,528
    float*          BI  = (float*)(ws + 6422528);           // 6,422,528
    float*          CC  = (float*)(ws + 12845056);          // 32,768
    float*          rel = (float*)(ws + 12877824);          // 32,768
    unsigned short* pW  = (unsigned short*)(ws + 12910592); // 3*65536*2 = 393,216

    hipMemsetAsync(rel, 0, NIMG * GH * sizeof(float), stream);
    k_cc<<<NIMG, 256, 0, stream>>>(code, gw0, gb0, CC);
    k_ajbi<<<NIMG * O, 256, 0, stream>>>(x, gw0, CC, AJ, BI);
    k_pack<<<768, 256, 0, stream>>>(gw1, gw2, gw3, pW);
    k_main<<<GRID, 512, 0, stream>>>(AJ, BI, pW, gb1, gb2, gb3, rel);
    k_fmlp<<<NIMG, 256, 0, stream>>>(rel, fw0, fb0, fw1, fb1, fw2, fb2, out);
}

// Round 10
// 848.052 us; speedup vs baseline: 2.1854x; 2.1854x over previous
//
#include <hip/hip_runtime.h>
#include <hip/hip_bf16.h>

// ---------------------------------------------------------------------------
// RelationalNetwork: N=32, C=24, H=W=14, O=196, HD=128, GH=256, AS=28
// pairs[n,i,j] = [feats[n,j](26), feats[n,i](26), code[n](128)]  (D_IN=180)
// h1 = relu(AJ'[n,j] + BI[n,i])        AJ' has CC (code-term) + gb0 folded in
// h  = relu(h@gw{1,2,3}+gb)            fused, bf16 MFMA 32x32x16, LDS-resident
// relations[n] = sum over 196^2 pairs  -> head MLP (fp32, tiny)
//
// Round 10: stream independence. r9's persistence spilled -> 26MB live
// scratch thrashed per-XCD L2 -> 4.45GB HBM fetch (revert persistence,
// lesson logged). Six spill-free rounds all sit at 510-546us with 2 fat
// 8-wave blocks/CU: block-wide barriers drain half the CU each time.
// Fix: 4-wave 256-thread blocks, 32KB LDS, (256,4) -> 4 INDEPENDENT
// blocks/CU (same 16 waves/CU): one block's barrier overlaps 3 others'
// MFMAs. Wave tile 64x64 (r6-proven 64 AGPR + 64 VGPR fit). Epilogue:
// 4-col-packed b64 stores (bank audit: old b32 was 4-way conflicted via
// l15^8 aliasing; 8B pack is exactly conflict-free). k_cc+k_pack merged.
// Tripwire: WRITE_SIZE >> 25MB => spill => revert to 8-wave (512,4).
// ---------------------------------------------------------------------------

typedef __attribute__((ext_vector_type(8))) short short8;
typedef __attribute__((ext_vector_type(16))) float f32x16;

#define NIMG 32
#define O 196
#define GH 256
#define AS 28
#define ROWS 64
#define CHUNKS 601          // 600*64 + 16 = 38416 (tail chunk: 16 valid rows)

#define SWZ16(row) (((row) & 15) << 4)

static __device__ __forceinline__ unsigned short f2bf(float f) {
    __hip_bfloat16 h = __float2bfloat16(f);
    return *reinterpret_cast<unsigned short*>(&h);
}

// ---- merged setup: blocks 0..767 pack gw1/2/3; blocks 768..799 compute CC --
// pack: elem offset = L*65536 + nt*8192 + ks*512 + lane*8 + e
//       value = W[ks*16 + (lane>>5)*8 + e][nt*32 + (lane&31)]
// (serves as either operand: B-frag for W, or A-frag for W^T under swap)
__global__ void k_setup(const float* __restrict__ gw1, const float* __restrict__ gw2,
                        const float* __restrict__ gw3, unsigned short* __restrict__ pW,
                        const float* __restrict__ code, const float* __restrict__ gw0,
                        const float* __restrict__ gb0, float* __restrict__ CC) {
    if (blockIdx.x < 768) {
        const int idx = blockIdx.x * 256 + threadIdx.x;     // 3*65536 total
        const int L = idx >> 16;
        const int rem = idx & 0xFFFF;
        const int e = rem & 7;
        const int lane = (rem >> 3) & 63;
        const int ks = (rem >> 9) & 15;
        const int nt = rem >> 13;                            // 0..7 (col 32-slice)
        const int k = ks * 16 + ((lane >> 5) << 3) + e;
        const int col = nt * 32 + (lane & 31);
        const float* W = (L == 0) ? gw1 : (L == 1) ? gw2 : gw3;
        pW[idx] = f2bf(W[k * GH + col]);
    } else {
        const int n = blockIdx.x - 768, g = threadIdx.x;
        __shared__ float cs[128];
        if (g < 128) cs[g] = code[n * 128 + g];
        __syncthreads();
        float acc = gb0[g];
        for (int k = 0; k < 128; ++k) acc = fmaf(cs[k], gw0[(52 + k) * GH + g], acc);
        CC[n * GH + g] = acc;
    }
}

// ---- setup kernel A: AJ'[n,p,g] (includes CC), BI[n,p,g] -------------------
__global__ void k_ajbi(const float* __restrict__ x, const float* __restrict__ gw0,
                       const float* __restrict__ CC,
                       float* __restrict__ AJ, float* __restrict__ BI) {
    const int np = blockIdx.x;            // n*196 + p
    const int n = np / O, p = np - n * O;
    const int g = threadIdx.x;
    __shared__ float fs[26];
    if (g < 24)       fs[g]  = x[(n * 24 + g) * O + p];
    else if (g == 24) fs[24] = -7.0f + (float)(p / 14) * (14.0f / 13.0f);
    else if (g == 25) fs[25] = -7.0f + (float)(p % 14) * (14.0f / 13.0f);
    __syncthreads();
    float aj = CC[n * GH + g], bi = 0.f;
#pragma unroll
    for (int c = 0; c < 26; ++c) {
        const float f = fs[c];
        aj = fmaf(f, gw0[c * GH + g], aj);
        bi = fmaf(f, gw0[(26 + c) * GH + g], bi);
    }
    AJ[np * GH + g] = aj;
    BI[np * GH + g] = bi;
}

// ---- main fused kernel: 4 waves, 64-row chunk, 3 layers + sum-pool ---------
__global__ __launch_bounds__(256, 4) void k_main(
    const float* __restrict__ AJ, const float* __restrict__ BI,
    const unsigned short* __restrict__ pW,
    const float* __restrict__ gb1, const float* __restrict__ gb2,
    const float* __restrict__ gb3, float* __restrict__ rel) {
    // 64 rows x 256 cols bf16, swizzled byte ^= SWZ16(row). 32 KiB.
    __shared__ __attribute__((aligned(16))) unsigned short h[ROWS * GH];

    const int blk = blockIdx.x;           // n*601 + chunk
    const int n = blk / CHUNKS;
    const int chunk = blk - n * CHUNKS;
    const int row_base = chunk * ROWS;
    const int t = threadIdx.x;
    const int wave = t >> 6;              // 0..3 (= cols wave*64 .. +63)
    const int lane = t & 63;
    const int l31 = lane & 31;
    const int hi = lane >> 5;
    const int l15 = lane & 15;
    const bool tail = (chunk == CHUNKS - 1);

    // ---- phase 0: h1 = relu(AJ'[j] + BI[i]) -> h (bf16, swizzled) ----
    // Each wave writes 16 rows (r = wave + 4e), full 256-col row per iter.
    {
        const int i0 = row_base / O;
        const int j00 = row_base - i0 * O;
        const int i1 = min(i0 + 1, O - 1);
        const float4 bi0 = *(const float4*)&BI[(n * O + i0) * GH + lane * 4];
        const float4 bi1 = *(const float4*)&BI[(n * O + i1) * GH + lane * 4];
#pragma unroll
        for (int e = 0; e < 16; ++e) {
            const int r = wave + e * 4;
            const int jj = j00 + r;                 // one wrap max
            const bool wrap = (jj >= O);
            const int j = wrap ? jj - O : jj;       // tail garbage rows; masked later
            const float4 aj = *(const float4*)&AJ[(n * O + j) * GH + lane * 4];
            const float4 bi = wrap ? bi1 : bi0;
            const unsigned lo = (unsigned)f2bf(fmaxf(aj.x + bi.x, 0.f)) |
                                ((unsigned)f2bf(fmaxf(aj.y + bi.y, 0.f)) << 16);
            const unsigned hh = (unsigned)f2bf(fmaxf(aj.z + bi.z, 0.f)) |
                                ((unsigned)f2bf(fmaxf(aj.w + bi.w, 0.f)) << 16);
            const int byteoff = r * 512 + ((lane * 8) ^ SWZ16(r));
            uint2 dd; dd.x = lo; dd.y = hh;
            *(uint2*)((char*)h + byteoff) = dd;
        }
    }
    __syncthreads();

    const int X = SWZ16(l15);             // rows l31 and l31+32 share this
    const int hi16 = hi << 4;
    const int arow = l31 * 512;
    const int s0 = wave * 2, s1 = wave * 2 + 1;   // wave's two 32-col W slices

    // K-loop: 2 ds_reads + 4 MFMA per step; 2-deep W prefetch per slice.
    auto kloop = [&](const short8* w0, const short8* w1,
                     f32x16& aA0, f32x16& aA1, f32x16& aB0, f32x16& aB1,
                     bool swapped) {
        short8 p0a = w0[lane], p0b = w0[64 + lane];
        short8 p1a = w1[lane], p1b = w1[64 + lane];
        const char* hb = (const char*)h + arow;
#pragma unroll
        for (int ks = 0; ks < 16; ++ks) {
            const short8 W0 = p0a, W1 = p1a;
            p0a = p0b; p1a = p1b;
            if (ks < 14) { p0b = w0[(ks + 2) * 64 + lane]; p1b = w1[(ks + 2) * 64 + lane]; }
            const int off = (ks * 32 + hi16) ^ X;
            const short8 h0 = *(const short8*)(hb + off);
            const short8 h1 = *(const short8*)(hb + off + 16384);   // +32 rows
            __builtin_amdgcn_s_setprio(1);
            if (swapped) {
                aA0 = __builtin_amdgcn_mfma_f32_32x32x16_bf16(W0, h0, aA0, 0, 0, 0);
                aA1 = __builtin_amdgcn_mfma_f32_32x32x16_bf16(W0, h1, aA1, 0, 0, 0);
                aB0 = __builtin_amdgcn_mfma_f32_32x32x16_bf16(W1, h0, aB0, 0, 0, 0);
                aB1 = __builtin_amdgcn_mfma_f32_32x32x16_bf16(W1, h1, aB1, 0, 0, 0);
            } else {
                aA0 = __builtin_amdgcn_mfma_f32_32x32x16_bf16(h0, W0, aA0, 0, 0, 0);
                aA1 = __builtin_amdgcn_mfma_f32_32x32x16_bf16(h1, W0, aA1, 0, 0, 0);
                aB0 = __builtin_amdgcn_mfma_f32_32x32x16_bf16(h0, W1, aB0, 0, 0, 0);
                aB1 = __builtin_amdgcn_mfma_f32_32x32x16_bf16(h1, W1, aB1, 0, 0, 0);
            }
            __builtin_amdgcn_s_setprio(0);
        }
    };

    // swapped epilogue: C'[reg -> W-col, lane -> h-row]. regs 4q..4q+3 are
    // 4 consecutive W-cols -> one 8B (b64) store; bank-exact, conflict-free.
    auto epi = [&](const f32x16& aA0, const f32x16& aA1,
                   const f32x16& aB0, const f32x16& aB1, const float* gb) {
        char* hc = (char*)h;
#pragma unroll
        for (int q = 0; q < 4; ++q) {
            const float4 bA = *(const float4*)&gb[s0 * 32 + 8 * q + 4 * hi];
            const float4 bB = *(const float4*)&gb[s1 * 32 + 8 * q + 4 * hi];
            const int r0 = q * 4;
            uint2 vA0, vA1, vB0, vB1;
            vA0.x = (unsigned)f2bf(fmaxf(aA0[r0] + bA.x, 0.f)) |
                    ((unsigned)f2bf(fmaxf(aA0[r0 + 1] + bA.y, 0.f)) << 16);
            vA0.y = (unsigned)f2bf(fmaxf(aA0[r0 + 2] + bA.z, 0.f)) |
                    ((unsigned)f2bf(fmaxf(aA0[r0 + 3] + bA.w, 0.f)) << 16);
            vA1.x = (unsigned)f2bf(fmaxf(aA1[r0] + bA.x, 0.f)) |
                    ((unsigned)f2bf(fmaxf(aA1[r0 + 1] + bA.y, 0.f)) << 16);
            vA1.y = (unsigned)f2bf(fmaxf(aA1[r0 + 2] + bA.z, 0.f)) |
                    ((unsigned)f2bf(fmaxf(aA1[r0 + 3] + bA.w, 0.f)) << 16);
            vB0.x = (unsigned)f2bf(fmaxf(aB0[r0] + bB.x, 0.f)) |
                    ((unsigned)f2bf(fmaxf(aB0[r0 + 1] + bB.y, 0.f)) << 16);
            vB0.y = (unsigned)f2bf(fmaxf(aB0[r0 + 2] + bB.z, 0.f)) |
                    ((unsigned)f2bf(fmaxf(aB0[r0 + 3] + bB.w, 0.f)) << 16);
            vB1.x = (unsigned)f2bf(fmaxf(aB1[r0] + bB.x, 0.f)) |
                    ((unsigned)f2bf(fmaxf(aB1[r0 + 1] + bB.y, 0.f)) << 16);
            vB1.y = (unsigned)f2bf(fmaxf(aB1[r0 + 2] + bB.z, 0.f)) |
                    ((unsigned)f2bf(fmaxf(aB1[r0 + 3] + bB.w, 0.f)) << 16);
            const int cA = (s0 * 64 + 16 * q + 8 * hi) ^ X;   // swizzled col byte
            const int cB = (s1 * 64 + 16 * q + 8 * hi) ^ X;
            *(uint2*)(hc + arow + cA) = vA0;                  // rows 0..31
            *(uint2*)(hc + arow + cB) = vB0;
            *(uint2*)(hc + arow + 16384 + cA) = vA1;          // rows 32..63
            *(uint2*)(hc + arow + 16384 + cB) = vB1;
        }
    };

    const f32x16 z = {0.f,0.f,0.f,0.f,0.f,0.f,0.f,0.f,0.f,0.f,0.f,0.f,0.f,0.f,0.f,0.f};
    const short8* wl = (const short8*)pW;

    // ---- layer 1 (swapped) ----
    f32x16 aA0 = z, aA1 = z, aB0 = z, aB1 = z;
    kloop(wl + s0 * 1024, wl + s1 * 1024, aA0, aA1, aB0, aB1, true);
    __syncthreads();                      // all reads of h done
    epi(aA0, aA1, aB0, aB1, gb1);
    __syncthreads();                      // all writes of h done

    // ---- layer 2 (swapped) ----
    aA0 = z; aA1 = z; aB0 = z; aB1 = z;
    kloop(wl + 8192 + s0 * 1024, wl + 8192 + s1 * 1024, aA0, aA1, aB0, aB1, true);
    __syncthreads();
    epi(aA0, aA1, aB0, aB1, gb2);
    __syncthreads();

    // ---- layer 3 (unswapped): bias+relu+column-sum -> atomic ----
    aA0 = z; aA1 = z; aB0 = z; aB1 = z;
    kloop(wl + 16384 + s0 * 1024, wl + 16384 + s1 * 1024, aA0, aA1, aB0, aB1, false);
    {
        const float biasA = gb3[s0 * 32 + l31];
        const float biasB = gb3[s1 * 32 + l31];
        float sA = 0.f, sB = 0.f;
        if (!tail) {
#pragma unroll
            for (int r = 0; r < 16; ++r) {
                sA += fmaxf(aA0[r] + biasA, 0.f) + fmaxf(aA1[r] + biasA, 0.f);
                sB += fmaxf(aB0[r] + biasB, 0.f) + fmaxf(aB1[r] + biasB, 0.f);
            }
        } else {
            // valid rows 0..15 -> tile0 regs 0..7 ((r&3)+8*(r>>2)+4hi < 16)
#pragma unroll
            for (int r = 0; r < 8; ++r) {
                sA += fmaxf(aA0[r] + biasA, 0.f);
                sB += fmaxf(aB0[r] + biasB, 0.f);
            }
        }
        sA += __shfl_xor(sA, 32);
        sB += __shfl_xor(sB, 32);
        if (hi == 0) {
            atomicAdd(&rel[n * GH + s0 * 32 + l31], sA);
            atomicAdd(&rel[n * GH + s1 * 32 + l31], sB);
        }
    }
}

// ---- head MLP (fp32, tiny): relations -> logits ----------------------------
__global__ void k_fmlp(const float* __restrict__ rel,
                       const float* __restrict__ fw0, const float* __restrict__ fb0,
                       const float* __restrict__ fw1, const float* __restrict__ fb1,
                       const float* __restrict__ fw2, const float* __restrict__ fb2,
                       float* __restrict__ out) {
    __shared__ float b0[GH], b1[GH];
    const int n = blockIdx.x, g = threadIdx.x;
    b0[g] = rel[n * GH + g];
    __syncthreads();
    float a = fb0[g];
    for (int k = 0; k < GH; ++k) a = fmaf(b0[k], fw0[k * GH + g], a);
    b1[g] = fmaxf(a, 0.f);
    __syncthreads();
    float c = fb1[g];
    for (int k = 0; k < GH; ++k) c = fmaf(b1[k], fw1[k * GH + g], c);
    b0[g] = fmaxf(c, 0.f);
    __syncthreads();
    if (g < AS) {
        float o = fb2[g];
        for (int k = 0; k < GH; ++k) o = fmaf(b0[k], fw2[k * AS + g], o);
        out[n * AS + g] = o;
    }
}

// ---------------------------------------------------------------------------
extern "C" void kernel_launch(void* const* d_in, const int* in_sizes, int n_in,
                              void* d_out, int out_size, void* d_ws, size_t ws_size,
                              hipStream_t stream) {
    const float* x    = (const float*)d_in[0];
    const float* code = (const float*)d_in[1];
    const float* gw0  = (const float*)d_in[2];
    const float* gb0  = (const float*)d_in[3];
    const float* gw1  = (const float*)d_in[4];
    const float* gb1  = (const float*)d_in[5];
    const float* gw2  = (const float*)d_in[6];
    const float* gb2  = (const float*)d_in[7];
    const float* gw3  = (const float*)d_in[8];
    const float* gb3  = (const float*)d_in[9];
    const float* fw0  = (const float*)d_in[10];
    const float* fb0  = (const float*)d_in[11];
    const float* fw1  = (const float*)d_in[12];
    const float* fb1  = (const float*)d_in[13];
    const float* fw2  = (const float*)d_in[14];
    const float* fb2  = (const float*)d_in[15];
    float* out = (float*)d_out;

    char* ws = (char*)d_ws;
    // workspace layout (16B aligned)
    float*          AJ  = (float*)(ws + 0);                 // 32*196*256*4 = 6,422,528
    float*          BI  = (float*)(ws + 6422528);           // 6,422,528
    float*          CC  = (float*)(ws + 12845056);          // 32,768
    float*          rel = (float*)(ws + 12877824);          // 32,768
    unsigned short* pW  = (unsigned short*)(ws + 12910592); // 3*65536*2 = 393,216

    hipMemsetAsync(rel, 0, NIMG * GH * sizeof(float), stream);
    k_setup<<<800, 256, 0, stream>>>(gw1, gw2, gw3, pW, code, gw0, gb0, CC);
    k_ajbi<<<NIMG * O, 256, 0, stream>>>(x, gw0, CC, AJ, BI);
    k_main<<<NIMG * CHUNKS, 256, 0, stream>>>(AJ, BI, pW, gb1, gb2, gb3, rel);
    k_fmlp<<<NIMG, 256, 0, stream>>>(rel, fw0, fb0, fw1, fb1, fw2, fb2, out);
}